// Round 15
// baseline (90.577 us; speedup 1.0000x reference)
//
#include <hip/hip_runtime.h>

#define B_   64
#define T_   2000
#define RNN_ 1024
#define EMB_ 512
#define ATT_ 128
#define CH_  8
#define K_   21
#define PL_  11
#define GSZ  168   // CH_*K_
#define CCHK 64    // rows per fused chunk
#define NCC  32    // chunks per batch (last has 16 valid rows)

typedef float vf4 __attribute__((ext_vector_type(4)));

__device__ __forceinline__ float fast_tanh(float x) {
    float ax = fabsf(x);
    float e  = __expf(2.0f * ax);
    float t  = 1.0f - 2.0f / (e + 1.0f);
    return copysignf(t, x);
}

// ---- kernel 1: zero out_ctx + G = tanh(q @ W_w^T + W_b) @ V_w^T ----
__global__ __launch_bounds__(256) void k_gen_dyn(
    const float* __restrict__ q, const float* __restrict__ Ww,
    const float* __restrict__ Wb, const float* __restrict__ Vw,
    float* __restrict__ G, float* __restrict__ out_ctx)
{
    __shared__ float sq[RNN_];
    __shared__ float part[256];
    __shared__ float sh[ATT_];
    const int b = blockIdx.x, tid = threadIdx.x;
    for (int i = tid; i < EMB_; i += 256) out_ctx[b * EMB_ + i] = 0.f;
    for (int i = tid; i < RNN_; i += 256) sq[i] = q[b * RNN_ + i];
    __syncthreads();
    {
        const int row = tid & 127, half = tid >> 7;        // 2-way K split
        const float4* wr = reinterpret_cast<const float4*>(Ww + row * RNN_ + half * (RNN_ / 2));
        const float4* qr = reinterpret_cast<const float4*>(sq + half * (RNN_ / 2));
        float acc = 0.f;
        #pragma unroll 8
        for (int i = 0; i < RNN_ / 8; ++i) {
            float4 w4 = wr[i], q4 = qr[i];
            acc += w4.x * q4.x + w4.y * q4.y + w4.z * q4.z + w4.w * q4.w;
        }
        part[tid] = acc;
    }
    __syncthreads();
    if (tid < ATT_) sh[tid] = fast_tanh(part[tid] + part[tid + 128] + Wb[tid]);
    __syncthreads();
    for (int o = tid; o < GSZ; o += 256) {
        const float4* vr = reinterpret_cast<const float4*>(Vw + o * ATT_);
        const float4* hr = reinterpret_cast<const float4*>(sh);
        float acc = 0.f;
        #pragma unroll 8
        for (int i = 0; i < ATT_ / 4; ++i) {
            float4 v4 = vr[i], h4 = hr[i];
            acc += v4.x * h4.x + v4.y * h4.y + v4.z * h4.z + v4.w * h4.w;
        }
        G[b * GSZ + o] = acc;
    }
}

// ---- kernel 2: fused energy + UNNORMALIZED stream + merge, with early preload ----
__global__ __launch_bounds__(256, 8) void k_eng_stream(
    const float* __restrict__ a,  const float* __restrict__ G,
    const float* __restrict__ Fw, const float* __restrict__ Uw,
    const float* __restrict__ Tw, const float* __restrict__ Tb,
    const float* __restrict__ vw, const float* __restrict__ P,
    const unsigned char* __restrict__ mask, const float* __restrict__ mem,
    float* __restrict__ pws, float* __restrict__ sred,
    float* __restrict__ out_ctx)
{
    __shared__ union {
        struct {
            float FG[K_ * 16];     // [k][16]: c<8=F_w[c][k], c>=8=G[b][(c-8)*21+k]
            float UT[ATT_ * 16];   // [d][16]: c<8=U_w[d][c], c>=8=T_w[d][c-8]
            float Tb[ATT_]; float V[ATT_]; float Pr[PL_];
            float Q[4 * CCHK]; float red[4];
        } E;
        struct { vf4 part[2][EMB_ / 4]; } C;
    } sm;
    __shared__ float sA[CCHK + K_ - 1];  // 84 window
    __shared__ float sp[CCHK];           // raw p for this chunk

    const int b = blockIdx.x, c = blockIdx.y, tid = threadIdx.x;
    const int t0 = c * CCHK;
    const int nvalid = min(CCHK, T_ - t0);
    const int tloc = tid & (CCHK - 1);
    const int qq = tid >> 6;             // 0..3 -> dims [qq*32, qq*32+32)
    const int col = tid & 127, rp = tid >> 7;

    // ---- early preload: rows rp, rp+2 of this block's mem slice (issue now,
    // first used after the energy phase — HBM latency hides under VALU) ----
    const float* basep = mem + ((size_t)(b * T_ + t0)) * EMB_ + col * 4;
    vf4 pre0 = *reinterpret_cast<const vf4*>(basep + (size_t)rp * EMB_);
    vf4 pre1 = *reinterpret_cast<const vf4*>(basep + (size_t)(rp + 2) * EMB_);

    // ---- staging ----
    for (int j = tid; j < CCHK + K_ - 1; j += 256) {
        int idx = t0 - 10 + j;
        sA[j] = (idx >= 0 && idx < T_) ? a[b * T_ + idx] : 0.f;
    }
    for (int j = tid; j < 2 * GSZ; j += 256) {
        if (j < GSZ) sm.E.FG[(j % K_) * 16 + (j / K_)] = Fw[j];
        else { int jj = j - GSZ; sm.E.FG[(jj % K_) * 16 + 8 + (jj / K_)] = G[b * GSZ + jj]; }
    }
    for (int j = tid; j < ATT_ * CH_; j += 256) {
        int d = j >> 3, ch = j & 7;
        sm.E.UT[d * 16 + ch]     = Uw[j];
        sm.E.UT[d * 16 + 8 + ch] = Tw[j];
    }
    if (tid < ATT_) { sm.E.Tb[tid] = Tb[tid]; sm.E.V[tid] = vw[tid]; }
    if (tid < PL_)  sm.E.Pr[tid] = P[tid];
    __syncthreads();

    // ---- conv features + quarter-MLP ----
    {
        float fg[16];
        #pragma unroll
        for (int i = 0; i < 16; ++i) fg[i] = 0.f;
        #pragma unroll
        for (int k = 0; k < K_; ++k) {
            float av = sA[tloc + k];
            const vf4* fp = reinterpret_cast<const vf4*>(&sm.E.FG[k * 16]);
            vf4 x0 = fp[0], x1 = fp[1], x2 = fp[2], x3 = fp[3];
            fg[0]  += x0.x * av; fg[1]  += x0.y * av; fg[2]  += x0.z * av; fg[3]  += x0.w * av;
            fg[4]  += x1.x * av; fg[5]  += x1.y * av; fg[6]  += x1.z * av; fg[7]  += x1.w * av;
            fg[8]  += x2.x * av; fg[9]  += x2.y * av; fg[10] += x2.z * av; fg[11] += x2.w * av;
            fg[12] += x3.x * av; fg[13] += x3.y * av; fg[14] += x3.z * av; fg[15] += x3.w * av;
        }
        float accQ = 0.f;
        const int d0 = qq * 32;
        #pragma unroll 4
        for (int dd = 0; dd < 32; ++dd) {
            const int d = d0 + dd;
            const vf4* up = reinterpret_cast<const vf4*>(&sm.E.UT[d * 16]);
            vf4 u0 = up[0], u1 = up[1], u2 = up[2], u3 = up[3];
            float s0 = u0.x * fg[0]  + u0.y * fg[1]  + u0.z * fg[2]  + u0.w * fg[3];
            float s1 = u1.x * fg[4]  + u1.y * fg[5]  + u1.z * fg[6]  + u1.w * fg[7];
            float s2 = u2.x * fg[8]  + u2.y * fg[9]  + u2.z * fg[10] + u2.w * fg[11];
            float s3 = u3.x * fg[12] + u3.y * fg[13] + u3.z * fg[14] + u3.w * fg[15];
            float s = (sm.E.Tb[d] + s0) + (s1 + s2) + s3;
            accQ += sm.E.V[d] * fast_tanh(s);
        }
        sm.E.Q[qq * CCHK + tloc] = accQ;
    }
    __syncthreads();

    // ---- p = exp(e) (defer-max: |e| bounded ~13, f32-safe) ----
    float pv = 0.f;
    if (tid < CCHK) {
        const int t = t0 + tid;
        if (t < T_ && !mask[b * T_ + min(t, T_ - 1)]) {
            float pp = 0.f;
            #pragma unroll
            for (int k = 0; k < PL_; ++k) pp += sm.E.Pr[k] * sA[tid + k];
            float e = (sm.E.Q[tid] + sm.E.Q[CCHK + tid])
                    + (sm.E.Q[2 * CCHK + tid] + sm.E.Q[3 * CCHK + tid])
                    + __logf(fmaxf(pp, 1e-6f));
            pv = __expf(e);
        }
        sp[tid] = pv;
        if (t0 + tid < T_) pws[b * T_ + t0 + tid] = pv;
    }
    float ssum = pv;
    #pragma unroll
    for (int off = 32; off > 0; off >>= 1) ssum += __shfl_xor(ssum, off);
    if ((tid & 63) == 0) sm.E.red[tid >> 6] = ssum;
    __syncthreads();
    if (tid == 0)
        sred[b * NCC + c] = sm.E.red[0] + sm.E.red[1] + sm.E.red[2] + sm.E.red[3];
    __syncthreads();   // all reads of sm.E done before union reuse as sm.C

    // ---- stream: preloaded rows first, then remaining, two chains ----
    {
        vf4 acc0 = sp[rp] * pre0;
        vf4 acc1 = sp[rp + 2] * pre1;
        if (nvalid == CCHK) {
            #pragma unroll
            for (int i = 1; i < CCHK / 4; ++i) {
                const int r0 = rp + 4 * i, r1 = rp + 4 * i + 2;
                vf4 m0 = *reinterpret_cast<const vf4*>(basep + (size_t)r0 * EMB_);
                vf4 m1 = *reinterpret_cast<const vf4*>(basep + (size_t)r1 * EMB_);
                acc0 += sp[r0] * m0;
                acc1 += sp[r1] * m1;
            }
        } else {
            for (int tt = rp + 4; tt < nvalid; tt += 2) {
                vf4 mv = *reinterpret_cast<const vf4*>(basep + (size_t)tt * EMB_);
                acc0 += sp[tt] * mv;
            }
        }
        sm.C.part[rp][col] = acc0 + acc1;
    }
    __syncthreads();
    if (tid < 128) {
        vf4 r = sm.C.part[0][tid];
        r += sm.C.part[1][tid];
        float* op = out_ctx + b * EMB_ + tid * 4;
        atomicAdd(op + 0, r.x); atomicAdd(op + 1, r.y);
        atomicAdd(op + 2, r.z); atomicAdd(op + 3, r.w);
    }
}

// ---- kernel 3: finalize (128 blocks, half-batch each) ----
__global__ __launch_bounds__(256) void k_final(
    const float* __restrict__ sred, const float* __restrict__ pws,
    float* __restrict__ out_ctx, float* __restrict__ out_w)
{
    __shared__ float sS;
    const int b = blockIdx.x >> 1, half = blockIdx.x & 1, tid = threadIdx.x;
    float v = (tid < NCC) ? sred[b * NCC + tid] : 0.f;
    #pragma unroll
    for (int off = 16; off > 0; off >>= 1) v += __shfl_xor(v, off);
    if (tid == 0) sS = v;
    __syncthreads();
    const float inv = 1.0f / sS;
    out_ctx[b * EMB_ + half * 256 + tid] *= inv;
    for (int j = tid; j < T_ / 2; j += 256) {
        const int t = half * (T_ / 2) + j;
        out_w[b * T_ + t] = pws[b * T_ + t] * inv;
    }
}

extern "C" void kernel_launch(void* const* d_in, const int* in_sizes, int n_in,
                              void* d_out, int out_size, void* d_ws, size_t ws_size,
                              hipStream_t stream)
{
    const float* q    = (const float*)d_in[0];
    const float* mem  = (const float*)d_in[1];
    const float* a    = (const float*)d_in[2];
    const unsigned char* mask = (const unsigned char*)d_in[3];
    const float* Ww = (const float*)d_in[4];
    const float* Wb = (const float*)d_in[5];
    const float* Vw = (const float*)d_in[6];
    const float* Fw = (const float*)d_in[7];
    const float* Uw = (const float*)d_in[8];
    const float* Tw = (const float*)d_in[9];
    const float* Tb = (const float*)d_in[10];
    const float* vw = (const float*)d_in[11];
    const float* P  = (const float*)d_in[12];

    float* out_ctx = (float*)d_out;           // [64*512]
    float* out_w   = out_ctx + B_ * EMB_;     // [64*2000]

    float* G    = (float*)d_ws;               // [64*168]
    float* sred = G + B_ * GSZ;               // [64*32]
    float* pws  = sred + B_ * NCC;            // [64*2000]

    k_gen_dyn<<<B_, 256, 0, stream>>>(q, Ww, Wb, Vw, G, out_ctx);
    k_eng_stream<<<dim3(B_, NCC), 256, 0, stream>>>(a, G, Fw, Uw, Tw, Tb, vw, P,
                                                    mask, mem, pws, sred, out_ctx);
    k_final<<<B_ * 2, 256, 0, stream>>>(sred, pws, out_ctx, out_w);
}

// Round 16
// 80.510 us; speedup vs baseline: 1.1250x; 1.1250x over previous
//
#include <hip/hip_runtime.h>

#define B_   64
#define T_   2000
#define RNN_ 1024
#define EMB_ 512
#define ATT_ 128
#define CH_  8
#define K_   21
#define PL_  11
#define GSZ  168   // CH_*K_
#define CCHK 64    // rows per fused chunk
#define NCC  32    // chunks per batch (last has 16 valid rows)

typedef float vf4 __attribute__((ext_vector_type(4)));

__device__ __forceinline__ float fast_tanh(float x) {
    float ax = fabsf(x);
    float e  = __expf(2.0f * ax);
    float t  = 1.0f - 2.0f / (e + 1.0f);
    return copysignf(t, x);
}

// ---- kernel 1: zero out_ctx + G = tanh(q @ W_w^T + W_b) @ V_w^T ----
__global__ __launch_bounds__(256) void k_gen_dyn(
    const float* __restrict__ q, const float* __restrict__ Ww,
    const float* __restrict__ Wb, const float* __restrict__ Vw,
    float* __restrict__ G, float* __restrict__ out_ctx)
{
    __shared__ float sq[RNN_];
    __shared__ float part[256];
    __shared__ float sh[ATT_];
    const int b = blockIdx.x, tid = threadIdx.x;
    for (int i = tid; i < EMB_; i += 256) out_ctx[b * EMB_ + i] = 0.f;
    for (int i = tid; i < RNN_; i += 256) sq[i] = q[b * RNN_ + i];
    __syncthreads();
    {
        const int row = tid & 127, half = tid >> 7;        // 2-way K split
        const float4* wr = reinterpret_cast<const float4*>(Ww + row * RNN_ + half * (RNN_ / 2));
        const float4* qr = reinterpret_cast<const float4*>(sq + half * (RNN_ / 2));
        float acc = 0.f;
        #pragma unroll 8
        for (int i = 0; i < RNN_ / 8; ++i) {
            float4 w4 = wr[i], q4 = qr[i];
            acc += w4.x * q4.x + w4.y * q4.y + w4.z * q4.z + w4.w * q4.w;
        }
        part[tid] = acc;
    }
    __syncthreads();
    if (tid < ATT_) sh[tid] = fast_tanh(part[tid] + part[tid + 128] + Wb[tid]);
    __syncthreads();
    for (int o = tid; o < GSZ; o += 256) {
        const float4* vr = reinterpret_cast<const float4*>(Vw + o * ATT_);
        const float4* hr = reinterpret_cast<const float4*>(sh);
        float acc = 0.f;
        #pragma unroll 8
        for (int i = 0; i < ATT_ / 4; ++i) {
            float4 v4 = vr[i], h4 = hr[i];
            acc += v4.x * h4.x + v4.y * h4.y + v4.z * h4.z + v4.w * h4.w;
        }
        G[b * GSZ + o] = acc;
    }
}

// ---- kernel 2: fused energy (4-way d-split) + UNNORMALIZED stream + merge ----
// p = exp(e) (defer-max, |e| bounded ~13), stream weighted by raw p,
// atomic-add unnormalized context. (256,8): 2048 blocks all co-resident,
// 32 waves/CU of stream depth.
__global__ __launch_bounds__(256, 8) void k_eng_stream(
    const float* __restrict__ a,  const float* __restrict__ G,
    const float* __restrict__ Fw, const float* __restrict__ Uw,
    const float* __restrict__ Tw, const float* __restrict__ Tb,
    const float* __restrict__ vw, const float* __restrict__ P,
    const unsigned char* __restrict__ mask, const float* __restrict__ mem,
    float* __restrict__ pws, float* __restrict__ sred,
    float* __restrict__ out_ctx)
{
    __shared__ union {
        struct {
            float FG[K_ * 16];     // [k][16]: c<8=F_w[c][k], c>=8=G[b][(c-8)*21+k]
            float UT[ATT_ * 16];   // [d][16]: c<8=U_w[d][c], c>=8=T_w[d][c-8]
            float Tb[ATT_]; float V[ATT_]; float Pr[PL_];
            float Q[4 * CCHK]; float red[4];
        } E;
        struct { vf4 part[2][EMB_ / 4]; } C;
    } sm;
    __shared__ float sA[CCHK + K_ - 1];  // 84 window (persists through E phase)
    __shared__ float sp[CCHK];           // raw p for this chunk

    const int b = blockIdx.x, c = blockIdx.y, tid = threadIdx.x;
    const int t0 = c * CCHK;
    const int nvalid = min(CCHK, T_ - t0);
    const int tloc = tid & (CCHK - 1);
    const int qq = tid >> 6;             // 0..3 -> dims [qq*32, qq*32+32)

    // ---- staging ----
    for (int j = tid; j < CCHK + K_ - 1; j += 256) {
        int idx = t0 - 10 + j;
        sA[j] = (idx >= 0 && idx < T_) ? a[b * T_ + idx] : 0.f;
    }
    for (int j = tid; j < 2 * GSZ; j += 256) {
        if (j < GSZ) sm.E.FG[(j % K_) * 16 + (j / K_)] = Fw[j];
        else { int jj = j - GSZ; sm.E.FG[(jj % K_) * 16 + 8 + (jj / K_)] = G[b * GSZ + jj]; }
    }
    for (int j = tid; j < ATT_ * CH_; j += 256) {
        int d = j >> 3, ch = j & 7;
        sm.E.UT[d * 16 + ch]     = Uw[j];
        sm.E.UT[d * 16 + 8 + ch] = Tw[j];
    }
    if (tid < ATT_) { sm.E.Tb[tid] = Tb[tid]; sm.E.V[tid] = vw[tid]; }
    if (tid < PL_)  sm.E.Pr[tid] = P[tid];
    __syncthreads();

    // ---- conv features (per-row, 4x redundant across qq) + quarter-MLP ----
    {
        float fg[16];
        #pragma unroll
        for (int i = 0; i < 16; ++i) fg[i] = 0.f;
        #pragma unroll
        for (int k = 0; k < K_; ++k) {
            float av = sA[tloc + k];
            const vf4* fp = reinterpret_cast<const vf4*>(&sm.E.FG[k * 16]);
            vf4 x0 = fp[0], x1 = fp[1], x2 = fp[2], x3 = fp[3];
            fg[0]  += x0.x * av; fg[1]  += x0.y * av; fg[2]  += x0.z * av; fg[3]  += x0.w * av;
            fg[4]  += x1.x * av; fg[5]  += x1.y * av; fg[6]  += x1.z * av; fg[7]  += x1.w * av;
            fg[8]  += x2.x * av; fg[9]  += x2.y * av; fg[10] += x2.z * av; fg[11] += x2.w * av;
            fg[12] += x3.x * av; fg[13] += x3.y * av; fg[14] += x3.z * av; fg[15] += x3.w * av;
        }
        float accQ = 0.f;
        const int d0 = qq * 32;
        #pragma unroll 4
        for (int dd = 0; dd < 32; ++dd) {
            const int d = d0 + dd;
            const vf4* up = reinterpret_cast<const vf4*>(&sm.E.UT[d * 16]);
            vf4 u0 = up[0], u1 = up[1], u2 = up[2], u3 = up[3];
            float s0 = u0.x * fg[0]  + u0.y * fg[1]  + u0.z * fg[2]  + u0.w * fg[3];
            float s1 = u1.x * fg[4]  + u1.y * fg[5]  + u1.z * fg[6]  + u1.w * fg[7];
            float s2 = u2.x * fg[8]  + u2.y * fg[9]  + u2.z * fg[10] + u2.w * fg[11];
            float s3 = u3.x * fg[12] + u3.y * fg[13] + u3.z * fg[14] + u3.w * fg[15];
            float s = (sm.E.Tb[d] + s0) + (s1 + s2) + s3;
            accQ += sm.E.V[d] * fast_tanh(s);
        }
        sm.E.Q[qq * CCHK + tloc] = accQ;
    }
    __syncthreads();

    // ---- p = exp(e) for rows tid < 64 ----
    float pv = 0.f;
    if (tid < CCHK) {
        const int t = t0 + tid;
        if (t < T_ && !mask[b * T_ + min(t, T_ - 1)]) {
            float pp = 0.f;
            #pragma unroll
            for (int k = 0; k < PL_; ++k) pp += sm.E.Pr[k] * sA[tid + k];
            float e = (sm.E.Q[tid] + sm.E.Q[CCHK + tid])
                    + (sm.E.Q[2 * CCHK + tid] + sm.E.Q[3 * CCHK + tid])
                    + __logf(fmaxf(pp, 1e-6f));
            pv = __expf(e);
        }
        sp[tid] = pv;
        if (t0 + tid < T_) pws[b * T_ + t0 + tid] = pv;
    }
    float ssum = pv;
    #pragma unroll
    for (int off = 32; off > 0; off >>= 1) ssum += __shfl_xor(ssum, off);
    if ((tid & 63) == 0) sm.E.red[tid >> 6] = ssum;
    __syncthreads();
    if (tid == 0)
        sred[b * NCC + c] = sm.E.red[0] + sm.E.red[1] + sm.E.red[2] + sm.E.red[3];
    __syncthreads();   // all reads of sm.E done before union reuse as sm.C

    // ---- stream 64 x 512 slice weighted by raw p, two chains, atomic merge ----
    {
        const int col = tid & 127, rp = tid >> 7;
        const float* basep = mem + ((size_t)(b * T_ + t0)) * EMB_ + col * 4;
        vf4 acc0 = {0.f, 0.f, 0.f, 0.f}, acc1 = {0.f, 0.f, 0.f, 0.f};
        if (nvalid == CCHK) {
            #pragma unroll
            for (int i = 0; i < CCHK / 4; ++i) {
                const int r0 = rp + 4 * i, r1 = rp + 4 * i + 2;
                vf4 m0 = *reinterpret_cast<const vf4*>(basep + (size_t)r0 * EMB_);
                vf4 m1 = *reinterpret_cast<const vf4*>(basep + (size_t)r1 * EMB_);
                acc0 += sp[r0] * m0;
                acc1 += sp[r1] * m1;
            }
        } else {
            for (int tt = rp; tt < nvalid; tt += 2) {
                vf4 mv = *reinterpret_cast<const vf4*>(basep + (size_t)tt * EMB_);
                acc0 += sp[tt] * mv;
            }
        }
        sm.C.part[rp][col] = acc0 + acc1;
    }
    __syncthreads();
    if (tid < 128) {
        vf4 r = sm.C.part[0][tid];
        r += sm.C.part[1][tid];
        float* op = out_ctx + b * EMB_ + tid * 4;
        atomicAdd(op + 0, r.x); atomicAdd(op + 1, r.y);
        atomicAdd(op + 2, r.z); atomicAdd(op + 3, r.w);
    }
}

// ---- kernel 3: finalize — S per batch, scale ctx and weights by 1/S ----
__global__ __launch_bounds__(256) void k_final(
    const float* __restrict__ sred, const float* __restrict__ pws,
    float* __restrict__ out_ctx, float* __restrict__ out_w)
{
    __shared__ float sS;
    const int b = blockIdx.x, tid = threadIdx.x;
    float v = (tid < NCC) ? sred[b * NCC + tid] : 0.f;
    #pragma unroll
    for (int off = 16; off > 0; off >>= 1) v += __shfl_xor(v, off);
    if (tid == 0) sS = v;
    __syncthreads();
    const float inv = 1.0f / sS;
    for (int i = tid; i < EMB_; i += 256) out_ctx[b * EMB_ + i] *= inv;
    for (int j = tid; j < T_; j += 256) out_w[b * T_ + j] = pws[b * T_ + j] * inv;
}

extern "C" void kernel_launch(void* const* d_in, const int* in_sizes, int n_in,
                              void* d_out, int out_size, void* d_ws, size_t ws_size,
                              hipStream_t stream)
{
    const float* q    = (const float*)d_in[0];
    const float* mem  = (const float*)d_in[1];
    const float* a    = (const float*)d_in[2];
    const unsigned char* mask = (const unsigned char*)d_in[3];
    const float* Ww = (const float*)d_in[4];
    const float* Wb = (const float*)d_in[5];
    const float* Vw = (const float*)d_in[6];
    const float* Fw = (const float*)d_in[7];
    const float* Uw = (const float*)d_in[8];
    const float* Tw = (const float*)d_in[9];
    const float* Tb = (const float*)d_in[10];
    const float* vw = (const float*)d_in[11];
    const float* P  = (const float*)d_in[12];

    float* out_ctx = (float*)d_out;           // [64*512]
    float* out_w   = out_ctx + B_ * EMB_;     // [64*2000]

    float* G    = (float*)d_ws;               // [64*168]
    float* sred = G + B_ * GSZ;               // [64*32]
    float* pws  = sred + B_ * NCC;            // [64*2000]

    k_gen_dyn<<<B_, 256, 0, stream>>>(q, Ww, Wb, Vw, G, out_ctx);
    k_eng_stream<<<dim3(B_, NCC), 256, 0, stream>>>(a, G, Fw, Uw, Tw, Tb, vw, P,
                                                    mask, mem, pws, sred, out_ctx);
    k_final<<<B_, 256, 0, stream>>>(sred, pws, out_ctx, out_w);
}